// Round 16
// baseline (428.039 us; speedup 1.0000x reference)
//
#include <hip/hip_runtime.h>
#include <cstdint>
#include <cstddef>

// Problem constants
#define N_TOK 4096
#define E_DIM 2048
#define NH    16
#define DH    128
#define KEXP  4
#define CAPN  1280
#define NTILE 20                 // CAPN/64
#define NQB   10                 // CAPN/128 (attn q-blocks)
#define QKV_STRIDE 6144          // fused QKV output row stride
#define SCALE_QK 0.08838834764831845f
#define LOG2E    1.4426950408889634f
#define NEG_BIG -1e30f

typedef __attribute__((ext_vector_type(4))) float f32x4;
typedef __attribute__((ext_vector_type(8))) short s16x8;

__device__ __forceinline__ float bf2f(unsigned short u){
  union{unsigned int i; float fl;} c; c.i = ((unsigned int)u)<<16; return c.fl;
}
__device__ __forceinline__ unsigned short f2bf(float x){
  union{float fl; unsigned int i;} c; c.fl=x;
  return (unsigned short)((c.i + 0x7FFFu + ((c.i>>16)&1u))>>16);
}
__device__ __forceinline__ f32x4 mfma_bf16(s16x8 a, s16x8 b, f32x4 c){
  asm("v_mfma_f32_16x16x32_bf16 %0, %1, %2, %0" : "+v"(c) : "v"(a), "v"(b));
  return c;
}
// async global->LDS 16B: LDS dest must be lane-linear (base + lane*16)
__device__ __forceinline__ void gl_lds16(const unsigned short* g, unsigned short* l){
  __builtin_amdgcn_global_load_lds(
      (const __attribute__((address_space(1))) unsigned int*)g,
      (__attribute__((address_space(3))) unsigned int*)l, 16, 0, 0);
}

// ---------------- conversions ----------------
__global__ __launch_bounds__(256) void conv_x_kernel(const float* __restrict__ x,
    unsigned short* __restrict__ hi, unsigned short* __restrict__ lo, int n4){
  int idx = blockIdx.x*256 + threadIdx.x;
  if (idx >= n4) return;
  float4 v = ((const float4*)x)[idx];
  float ar[4] = {v.x, v.y, v.z, v.w};
  union{ unsigned short u[4]; uint2 q; } H, L;
  #pragma unroll
  for(int i=0;i<4;i++){
    unsigned short h = f2bf(ar[i]);
    H.u[i] = h;
    L.u[i] = f2bf(ar[i] - bf2f(h));
  }
  ((uint2*)hi)[idx] = H.q;
  ((uint2*)lo)[idx] = L.q;
}

// transpose + f32->bf16 (optionally also lo residual). W[R][C] -> T[C][R]
__global__ __launch_bounds__(256) void tconv_kernel(const float* __restrict__ W,
    unsigned short* __restrict__ Thi, unsigned short* __restrict__ Tlo, int R, int C){
  __shared__ float t[32][33];
  int tx = threadIdx.x, ty = threadIdx.y;   // (32,8)
  int c0 = blockIdx.x*32, r0 = blockIdx.y*32;
  #pragma unroll
  for(int i=0;i<4;i++){
    int r = r0 + ty + i*8;
    t[ty+i*8][tx] = W[(size_t)r*C + c0 + tx];
  }
  __syncthreads();
  #pragma unroll
  for(int i=0;i<4;i++){
    int c = c0 + ty + i*8;
    float v = t[tx][ty+i*8];
    size_t o = (size_t)c*R + r0 + tx;
    unsigned short h = f2bf(v);
    Thi[o] = h;
    if (Tlo) Tlo[o] = f2bf(v - bf2f(h));
  }
}

// fused transpose of 4 ExE weights (Wq,Wk,Wv,Wo) -> contiguous [4][E][E] bf16
__global__ __launch_bounds__(256) void tconv4_kernel(const float* __restrict__ W0,
    const float* __restrict__ W1, const float* __restrict__ W2, const float* __restrict__ W3,
    unsigned short* __restrict__ out){
  __shared__ float t[32][33];
  int z = blockIdx.z;
  const float* W = (z==0)?W0 : (z==1)?W1 : (z==2)?W2 : W3;
  unsigned short* T = out + (size_t)z*E_DIM*E_DIM;
  int tx = threadIdx.x, ty = threadIdx.y;   // (32,8)
  int c0 = blockIdx.x*32, r0 = blockIdx.y*32;
  #pragma unroll
  for(int i=0;i<4;i++){
    int r = r0 + ty + i*8;
    t[ty+i*8][tx] = W[(size_t)r*E_DIM + c0 + tx];
  }
  __syncthreads();
  #pragma unroll
  for(int i=0;i<4;i++){
    int c = c0 + ty + i*8;
    T[(size_t)c*E_DIM + r0 + tx] = f2bf(t[tx][ty+i*8]);
  }
}

// ============ 128x128 BK=32-slab 3-slot-ring pipelined GEMM (T2+T3+T4+T5) ============
// 48KB LDS -> 3 blocks/CU (24 waves). QKV grid 1536 = exactly 2.0 occupancy rounds.
// 8 waves 2Mx4N, wave tile 64x32. Stage unit = {A 8KB, B 8KB} = 2 loads/thread.
// Ring safety as r11: read slot P%3, stage P+2 into (P+2)%3=(P-1)%3; steady vmcnt(2)
// (stage(P+1) complete, stage(P+2) rides); one barrier/phase; drains only at tail.
template<int OUTBF>
__global__ __launch_bounds__(512, 6) void gemm_p(
    const unsigned short* __restrict__ A, const unsigned short* __restrict__ Bt,
    void* __restrict__ Cp, int N, int Kd){
  __shared__ __align__(16) unsigned short lds[3*8192];   // 48 KB
  const int tid = threadIdx.x;
  const int w = tid>>6, lane = tid&63, g = lane>>4, r16 = lane&15;
  const int wm = w>>2, wn = w&3;                   // 2M x 4N waves, tile 64x32
  const int mb = blockIdx.y, nb = blockIdx.x;
  const unsigned short* Ab = A  + (size_t)mb*128*Kd;
  const unsigned short* Bb = Bt + (size_t)nb*128*Kd;
  const int PMAX = Kd >> 5;                        // K/32 phases

  f32x4 acc[4][2];
  #pragma unroll
  for(int i=0;i<4;i++){ acc[i][0]=f32x4{0.f,0.f,0.f,0.f}; acc[i][1]=f32x4{0.f,0.f,0.f,0.f}; }

  auto stageP = [&](int Pst, int slot){
    unsigned short* base = &lds[slot*8192];
    const int col = Pst*32;
    int row = tid>>2, ch = tid&3;                  // 128 rows x 4 chunks
    int sc = ch ^ ((row>>1)&3);
    gl_lds16(Ab + (size_t)row*Kd + col + sc*8, base + tid*8);
    gl_lds16(Bb + (size_t)row*Kd + col + sc*8, base + 4096 + tid*8);
  };
  const int xoff = (g ^ ((r16>>1)&3)) << 3;

  // prologue: phases 0,1 into slots 0,1; wait phase-0's unit (stage(1) rides)
  stageP(0,0); stageP(1,1);
  asm volatile("s_waitcnt vmcnt(2)" ::: "memory");
  __builtin_amdgcn_s_barrier();

  int sR = 0, sW = 2;
  for(int P=0; P<PMAX; ++P){
    const unsigned short* base = &lds[sR*8192];
    s16x8 af[4], bfv[2];
    #pragma unroll
    for(int mf=0;mf<4;mf++)
      af[mf] = *(const s16x8*)&base[(wm*64 + mf*16 + r16)*32 + xoff];
    #pragma unroll
    for(int nf=0;nf<2;nf++)
      bfv[nf] = *(const s16x8*)&base[4096 + (wn*32 + nf*16 + r16)*32 + xoff];
    if (P+2 < PMAX) stageP(P+2, sW);
    __builtin_amdgcn_s_setprio(1);
    #pragma unroll
    for(int mf=0;mf<4;mf++)
      #pragma unroll
      for(int nf=0;nf<2;nf++)
        acc[mf][nf] = mfma_bf16(af[mf], bfv[nf], acc[mf][nf]);
    __builtin_amdgcn_s_setprio(0);
    if      (P+2 < PMAX) asm volatile("s_waitcnt vmcnt(2)" ::: "memory");
    else                 asm volatile("s_waitcnt vmcnt(0)" ::: "memory");
    __builtin_amdgcn_s_barrier();
    sR = (sR==2) ? 0 : sR+1;
    sW = (sW==2) ? 0 : sW+1;
  }

  const int rowb = mb*128 + wm*64, colb = nb*128 + wn*32;
  #pragma unroll
  for(int mf=0;mf<4;mf++)
    #pragma unroll
    for(int nf=0;nf<2;nf++)
      #pragma unroll
      for(int r=0;r<4;r++){
        int rr = rowb + mf*16 + 4*g + r;
        int cc = colb + nf*16 + r16;
        size_t o = (size_t)rr*N + cc;
        if (OUTBF) ((unsigned short*)Cp)[o] = f2bf(acc[mf][nf][r]);
        else       ((float*)Cp)[o] = acc[mf][nf][r];
      }
}

// ============ router GEMM on the 3-slot-ring skeleton: H = gelu(x@Wr1+br1) ============
__global__ __launch_bounds__(256, 2) void gemm_router_p(
    const unsigned short* __restrict__ Ahi, const unsigned short* __restrict__ Alo,
    const unsigned short* __restrict__ Bhi, const unsigned short* __restrict__ Blo,
    const float* __restrict__ br1, float* __restrict__ H){
  __shared__ __align__(16) unsigned short lds[3*12288];   // 72 KB
  const int tid = threadIdx.x;
  const int w = tid>>6, lane = tid&63, g = lane>>4, r16 = lane&15;
  const int mb = blockIdx.y, nb = blockIdx.x;
  const unsigned short* AbH = Ahi + (size_t)mb*64*E_DIM;
  const unsigned short* AbL = Alo + (size_t)mb*64*E_DIM;
  const unsigned short* BbH = Bhi + (size_t)nb*128*E_DIM;
  const unsigned short* BbL = Blo + (size_t)nb*128*E_DIM;
  const int PMAX = E_DIM >> 5;   // 64

  f32x4 acc[4][2];
  #pragma unroll
  for(int i=0;i<4;i++){ acc[i][0]=f32x4{0.f,0.f,0.f,0.f}; acc[i][1]=f32x4{0.f,0.f,0.f,0.f}; }

  auto stageP = [&](int Pst, int slot){
    unsigned short* base = &lds[slot*12288];
    const int col = Pst*32;
    {
      int row = tid>>2, ch = tid&3;              // 64 rows x 4 chunks
      int sc = ch ^ ((row>>1)&3);
      size_t go = (size_t)row*E_DIM + col + sc*8;
      gl_lds16(AbH + go, base +        tid*8);
      gl_lds16(AbL + go, base + 2048 + tid*8);
    }
    #pragma unroll
    for(int i=0;i<2;i++){
      int n = i*256 + tid;                       // 128 rows x 4 chunks
      int row = n>>2, ch = n&3;
      int sc = ch ^ ((row>>1)&3);
      size_t go = (size_t)row*E_DIM + col + sc*8;
      gl_lds16(BbH + go, base + 4096 + n*8);
      gl_lds16(BbL + go, base + 8192 + n*8);
    }
  };
  const int xoff = (g ^ ((r16>>1)&3)) << 3;

  stageP(0,0); stageP(1,1);
  asm volatile("s_waitcnt vmcnt(6)" ::: "memory");
  __builtin_amdgcn_s_barrier();

  int sR = 0, sW = 2;
  for(int P=0; P<PMAX; ++P){
    const unsigned short* base = &lds[sR*12288];
    s16x8 ah[4], al[4], bh[2], bl[2];
    #pragma unroll
    for(int mf=0;mf<4;mf++){
      int ro = (mf*16 + r16)*32 + xoff;
      ah[mf] = *(const s16x8*)&base[ro];
      al[mf] = *(const s16x8*)&base[2048 + ro];
    }
    #pragma unroll
    for(int nf=0;nf<2;nf++){
      int rb = (w*32 + nf*16 + r16)*32 + xoff;
      bh[nf] = *(const s16x8*)&base[4096 + rb];
      bl[nf] = *(const s16x8*)&base[8192 + rb];
    }
    if (P+2 < PMAX) stageP(P+2, sW);
    __builtin_amdgcn_s_setprio(1);
    #pragma unroll
    for(int mf=0;mf<4;mf++)
      #pragma unroll
      for(int nf=0;nf<2;nf++){
        acc[mf][nf] = mfma_bf16(ah[mf], bh[nf], acc[mf][nf]);
        acc[mf][nf] = mfma_bf16(ah[mf], bl[nf], acc[mf][nf]);
        acc[mf][nf] = mfma_bf16(al[mf], bh[nf], acc[mf][nf]);
      }
    __builtin_amdgcn_s_setprio(0);
    if      (P+2 < PMAX) asm volatile("s_waitcnt vmcnt(6)" ::: "memory");
    else                 asm volatile("s_waitcnt vmcnt(0)" ::: "memory");
    __builtin_amdgcn_s_barrier();
    sR = (sR==2) ? 0 : sR+1;
    sW = (sW==2) ? 0 : sW+1;
  }

  const int rowb = mb*64, colb = nb*128 + w*32;
  #pragma unroll
  for(int mf=0;mf<4;mf++)
    #pragma unroll
    for(int nf=0;nf<2;nf++)
      #pragma unroll
      for(int r=0;r<4;r++){
        int rr = rowb + mf*16 + 4*g + r;
        int cc = colb + nf*16 + r16;
        float v = acc[mf][nf][r] + br1[cc];
        H[(size_t)rr*1024 + cc] = 0.5f*v*(1.0f + erff(v*0.70710678118654752f));
      }
}

// ---------------- router scores ----------------
__global__ __launch_bounds__(256) void scores_kernel(const float* __restrict__ h,
    const float* __restrict__ Wr2, const float* __restrict__ br2,
    float* __restrict__ scores, float* __restrict__ tokmax){
  int tid = threadIdx.x;
  int n = blockIdx.x*4 + (tid>>6);
  int lane = tid & 63;
  const float* hr = h + (size_t)n*1024;
  float s0=0,s1=0,s2=0,s3=0;
  #pragma unroll
  for(int i=0;i<16;i++){
    int j = lane + i*64;
    float hv = hr[j];
    float4 wv = *(const float4*)(Wr2 + (size_t)j*4);
    s0 += hv*wv.x; s1 += hv*wv.y; s2 += hv*wv.z; s3 += hv*wv.w;
  }
  #pragma unroll
  for(int m=32;m>=1;m>>=1){
    s0 += __shfl_xor(s0,m); s1 += __shfl_xor(s1,m);
    s2 += __shfl_xor(s2,m); s3 += __shfl_xor(s3,m);
  }
  if (lane==0){
    s0+=br2[0]; s1+=br2[1]; s2+=br2[2]; s3+=br2[3];
    scores[n*4+0]=s0; scores[n*4+1]=s1; scores[n*4+2]=s2; scores[n*4+3]=s3;
    tokmax[n]=fmaxf(fmaxf(s0,s1),fmaxf(s2,s3));
  }
}

__global__ __launch_bounds__(1024) void aux_kernel(const float* __restrict__ tokmax, float* __restrict__ out_aux){
  __shared__ float red[1024];
  int t = threadIdx.x;
  red[t] = tokmax[t] + tokmax[t+1024] + tokmax[t+2048] + tokmax[t+3072];
  __syncthreads();
  for(int k=512;k>=1;k>>=1){ if(t<k) red[t]+=red[t+k]; __syncthreads(); }
  if (t==0) out_aux[0] = -red[0]/4096.0f;
}

// ---------------- exact top-k via parallel rank ----------------
__global__ __launch_bounds__(256) void rank_kernel(const float* __restrict__ scores,
    int* __restrict__ topk_idx, float* __restrict__ topv, int* __restrict__ rank_of){
  __shared__ unsigned long long keys[4096];   // 32KB
  const int e = blockIdx.y, blk = blockIdx.x, tid = threadIdx.x;
  for(int i=tid;i<4096;i+=256){
    unsigned u = __float_as_uint(scores[i*4+e]);
    unsigned m = (u & 0x80000000u) ? ~u : (u | 0x80000000u);
    keys[i] = (((unsigned long long)m)<<32) | (unsigned)(4095-i);
  }
  __syncthreads();
  const int i = blk*256 + tid;
  const unsigned long long mykey = keys[i];
  int cnt = 0;
  #pragma unroll 8
  for(int j=0;j<4096;j++) cnt += (keys[j] > mykey) ? 1 : 0;
  if (cnt < CAPN){
    topk_idx[e*CAPN + cnt] = i;
    topv[e*CAPN + cnt]     = scores[i*4+e];
    rank_of[e*4096 + i]    = cnt;
  } else {
    rank_of[e*4096 + i]    = -1;
  }
}

// per-expert softmax over the CAPN sorted top values -> sel_w
__global__ __launch_bounds__(1024) void selw_kernel(const float* __restrict__ topv,
    float* __restrict__ sel_w){
  __shared__ float red[1024];
  const int e = blockIdx.x, t = threadIdx.x;
  const float mx = topv[e*CAPN];        // rank 0 == max
  float p0 = expf(topv[e*CAPN + t] - mx);
  float p1 = (t + 1024 < CAPN) ? expf(topv[e*CAPN + t + 1024] - mx) : 0.f;
  red[t] = p0 + p1;
  __syncthreads();
  for(int k=512;k>=1;k>>=1){ if(t<k) red[t]+=red[t+k]; __syncthreads(); }
  const float denom = red[0];
  sel_w[e*CAPN + t] = p0/denom;
  if (t + 1024 < CAPN) sel_w[e*CAPN + t + 1024] = p1/denom;
}

// ---------------- RoPE tables [CAPN][64] ----------------
__global__ __launch_bounds__(256) void rope_kernel(float* __restrict__ cosT, float* __restrict__ sinT){
  int idx = blockIdx.x*256 + threadIdx.x;
  int p = idx>>6, dm = idx&63;
  float inv = powf(10000.0f, -(float)dm/64.0f);
  float ang = (float)p*inv;
  cosT[idx]=cosf(ang);
  sinT[idx]=sinf(ang);
}

// ---------------- pre-gather + pre-rope K into swizzled tiles ----------------
__global__ __launch_bounds__(256) void prerope_k_kernel(const unsigned short* __restrict__ kb,
    const int* __restrict__ topk_idx, const float* __restrict__ cosT, const float* __restrict__ sinT,
    unsigned short* __restrict__ Kg){
  int idx = blockIdx.x*256 + threadIdx.x;   // exact 4*16*1280*16
  int ch = idx & 15;
  int rest = idx >> 4;
  int rank = rest % CAPN;
  int he = rest / CAPN;           // e*16+h
  int e = he >> 4, h = he & 15;
  int tok = topk_idx[e*CAPN + rank];
  int d0 = ch*8;
  const unsigned short* krow = kb + (size_t)tok*QKV_STRIDE + h*DH;
  unsigned short held[8], part[8];
  *(uint4*)held = *(const uint4*)(krow + d0);
  *(uint4*)part = *(const uint4*)(krow + (d0^64));
  const float* cr = cosT + rank*64;
  const float* sr = sinT + rank*64;
  float sgn = (d0<64) ? -1.f : 1.f;
  unsigned short outv[8];
  #pragma unroll
  for(int jj=0;jj<8;jj++){
    int dm = (d0+jj)&63;
    outv[jj] = f2bf(bf2f(held[jj])*cr[dm] + sgn*bf2f(part[jj])*sr[dm]);
  }
  int t = rank >> 6, row = rank & 63;
  size_t tbase = ((size_t)(he)*NTILE + t) * 8192;
  *(uint4*)(Kg + tbase + row*128 + ((ch ^ (row&7))<<3)) = *(uint4*)outv;
}

// ---------------- pre-gather + transpose V into swizzled tiles ----------------
__global__ __launch_bounds__(256) void prev_kernel(const unsigned short* __restrict__ vb,
    const int* __restrict__ topk_idx, unsigned short* __restrict__ Vg){
  __shared__ __align__(16) unsigned short T2[128][72];
  int bid = blockIdx.x;           // e*320 + h*20 + t
  int t = bid % NTILE, h = (bid/NTILE) & 15, e = bid/(NTILE*NH);
  int tid = threadIdx.x, lane = tid & 63, dchb = tid >> 6;
  int tok = topk_idx[e*CAPN + t*64 + lane];
  const unsigned short* vrow = vb + (size_t)tok*QKV_STRIDE + h*DH;
  #pragma unroll
  for(int i=0;i<4;i++){
    int d0 = (dchb + i*4)*8;
    unsigned short vv[8];
    *(uint4*)vv = *(const uint4*)(vrow + d0);
    #pragma unroll
    for(int j=0;j<8;j++) T2[d0+j][lane] = vv[j];   // lane-consecutive: conflict-free
  }
  __syncthreads();
  unsigned short* out = Vg + ((size_t)(e*NH+h)*NTILE + t)*8192;
  #pragma unroll
  for(int i=0;i<4;i++){
    int c = i*256 + tid;
    int d = c>>3, ch = c&7;
    *(uint4*)(out + d*64 + ((ch ^ (d&7))<<3)) = *(const uint4*)&T2[d][ch*8];
  }
}

// ---------------- gathered causal flash attention (128 Q rows / block, 8 waves) ----------------
// Balanced id->qb2 decode; per-lane l partials; T13 defer-max.
__global__ __launch_bounds__(512) void attn_kernel(
    const unsigned short* __restrict__ qb,
    const unsigned short* __restrict__ Kg, const unsigned short* __restrict__ Vg,
    const int* __restrict__ topk_idx, const float* __restrict__ sel_w,
    const float* __restrict__ cosT, const float* __restrict__ sinT,
    unsigned short* __restrict__ oexp){
  __shared__ __align__(16) unsigned short Ks[8192];
  __shared__ __align__(16) unsigned short Vs[8192];
  __shared__ __align__(16) unsigned short Ps[8][16][72];
  // balanced decode: layer0 qb2 {9,8,7,6}; layer1 {2,3,4,5} (pairwise sum 26); layer2 {0,1}
  const int id = blockIdx.x;
  int qb2, ehi;
  if (id < 512){
    const int layer = id >> 8;         // 0 or 1
    const int j = id & 255;
    const int cat = j >> 6;            // 0..3
    ehi = j & 63;
    qb2 = layer ? (2 + cat) : (9 - cat);
  } else {
    const int j = id - 512;
    qb2 = j >> 6;                      // 0 or 1
    ehi = j & 63;
  }
  const int e = ehi >> 4, hh = ehi & 15;
  const int tid = threadIdx.x, w = tid>>6, lane = tid&63, g = lane>>4, r16 = lane&15;
  const int* idxE = topk_idx + e*CAPN;
  const unsigned short* Kgb = Kg + (size_t)(e*NH+hh)*CAPN*DH;
  const unsigned short* Vgb = Vg + (size_t)(e*NH+hh)*CAPN*DH;
  const int ktmax = 2*qb2 + 1;
  const float THR = 8.0f*LOG2E;        // defer-max threshold (log2 domain)

  s16x8 aq[4];
  {
    int qr = qb2*128 + w*16 + r16;
    int tok = idxE[qr];
    const unsigned short* qrow = qb + (size_t)tok*QKV_STRIDE + hh*DH;
    const float* cr = cosT + qr*64;
    const float* sr = sinT + qr*64;
    #pragma unroll
    for(int s=0;s<4;s++){
      int d0 = s*32 + 8*g;
      unsigned short held[8], part[8];
      *(uint4*)held = *(const uint4*)(qrow + d0);
      *(uint4*)part = *(const uint4*)(qrow + (d0^64));
      float sgn = (d0<64) ? -1.f : 1.f;
      union{ s16x8 v; unsigned short u[8]; } fr;
      #pragma unroll
      for(int jj=0;jj<8;jj++){
        int dm = (d0+jj)&63;
        float val = bf2f(held[jj])*cr[dm] + sgn*bf2f(part[jj])*sr[dm];
        fr.u[jj] = f2bf(val * (SCALE_QK*LOG2E));
      }
      aq[s] = fr.v;
    }
  }
  float m_r[4], l_r[4];   // l_r: PER-LANE partial sums (reduced across 16 lanes at epilogue)
  f32x4 o[8];
  #pragma unroll
  for(int r=0;r<4;r++){ m_r[r]=-INFINITY; l_r[r]=0.f; }
  #pragma unroll
  for(int f2=0;f2<8;f2++) o[f2]=f32x4{0.f,0.f,0.f,0.f};

  for(int kt=0; kt<=ktmax; kt++){
    // stage K(kt), V(kt) into single buffers (prev readers done: barrier at tile end)
    {
      const unsigned short* Ksrc = Kgb + (size_t)kt*8192;
      const unsigned short* Vsrc = Vgb + (size_t)kt*8192;
      #pragma unroll
      for(int i=0;i<2;i++){ int c=i*512+tid; gl_lds16(Ksrc + c*8, &Ks[c*8]); }
      #pragma unroll
      for(int i=0;i<2;i++){ int c=i*512+tid; gl_lds16(Vsrc + c*8, &Vs[c*8]); }
    }
    asm volatile("s_waitcnt vmcnt(0)" ::: "memory");
    __builtin_amdgcn_s_barrier();
    // QK^T
    f32x4 sfr[4];
    __builtin_amdgcn_s_setprio(1);
    #pragma unroll
    for(int fc=0;fc<4;fc++){
      f32x4 a4 = f32x4{0.f,0.f,0.f,0.f};
      const int row = fc*16 + r16;
      #pragma unroll
      for(int s=0;s<4;s++){
        s16x8 bk = *(const s16x8*)&Ks[row*128 + (((s*4+g) ^ (r16&7))<<3)];
        a4 = mfma_bf16(aq[s], bk, a4);
      }
      sfr[fc] = a4;
    }
    __builtin_amdgcn_s_setprio(0);
    if (kt >= 2*qb2){   // diagonal tiles only
      #pragma unroll
      for(int fc=0;fc<4;fc++)
        #pragma unroll
        for(int r=0;r<4;r++){
          int qrank  = qb2*128 + w*16 + 4*g + r;
          int kvrank = kt*64 + fc*16 + r16;
          if (kvrank > qrank) sfr[fc][r] = NEG_BIG;
        }
    }
    // online softmax (exp2 domain), defer-max; l is per-lane partial (no sum shuffle)
    float corr[4];
    bool need = false;
    #pragma unroll
    for(int r=0;r<4;r++){
      float mx = fmaxf(fmaxf(sfr[0][r],sfr[1][r]), fmaxf(sfr[2][r],sfr[3][r]));
      #pragma unroll
      for(int mk=1;mk<16;mk<<=1) mx = fmaxf(mx, __shfl_xor(mx,mk));
      bool trig = mx > m_r[r] + THR;
      float nm = trig ? mx : m_r[r];
      need = need || trig;
      corr[r] = exp2f(m_r[r]-nm);   // == 1.0 when !trig
      m_r[r] = nm;
    }
    if (__any(need)){
      #pragma unroll
      for(int f2=0;f2<8;f2++)
        #pragma unroll
        for(int r=0;r<4;r++) o[f2][r] *= corr[r];
      #pragma unroll
      for(int r=0;r<4;r++) l_r[r] *= corr[r];
    }
    #pragma unroll
    for(int fc=0;fc<4;fc++)
      #pragma unroll
      for(int r=0;r<4;r++){
        float p = exp2f(sfr[fc][r] - m_r[r]);
        l_r[r] += p;
        Ps[w][4*g+r][fc*16+r16] = f2bf(p);
      }
    // PV (Ps wave-private: lgkm-ordered within wave)
    __builtin_amdgcn_s_setprio(1);
    #pragma unroll
    for(int ks=0;ks<2;ks++){
      s16x8 pa = *(const s16x8*)&Ps[w][r16][ks*32 + 8*g];
      #pragma unroll
      for(int fd=0;fd<8;fd++){
        const int row = fd*16 + r16;
        s16x8 vf = *(const s16x8*)&Vs[row*64 + (((ks*4+g) ^ (r16&7))<<3)];
        o[fd] = mfma_bf16(pa, vf, o[fd]);
      }
    }
    __builtin_amdgcn_s_setprio(0);
    if (kt < ktmax) __builtin_amdgcn_s_barrier();   // readers done -> next stage may overwrite
  }
  // epilogue: reduce per-lane l partials across the 16-lane row group, then scale+store
  #pragma unroll
  for(int r=0;r<4;r++){
    float ts = l_r[r];
    #pragma unroll
    for(int mk=1;mk<16;mk<<=1) ts += __shfl_xor(ts,mk);
    int qrank = qb2*128 + w*16 + 4*g + r;
    float fac = sel_w[e*CAPN + qrank] / ts;
    #pragma unroll
    for(int fd=0;fd<8;fd++){
      oexp[((size_t)(e*CAPN + qrank))*E_DIM + hh*DH + fd*16 + r16] = f2bf(o[fd][r]*fac);
    }
  }
}

// ---------------- scatter-accumulate over experts ----------------
__global__ __launch_bounds__(256) void acc_kernel(const unsigned short* __restrict__ oexp,
    const int* __restrict__ rank_of, unsigned short* __restrict__ accb){
  int n = blockIdx.x, t = threadIdx.x;
  int base = t*8;
  float s[8] = {0,0,0,0,0,0,0,0};
  #pragma unroll
  for(int e=0;e<4;e++){
    int r = rank_of[e*4096+n];
    if (r>=0){
      union{uint4 q; unsigned short u[8];} ld;
      ld.q = *(const uint4*)(oexp + ((size_t)(e*CAPN+r))*E_DIM + base);
      #pragma unroll
      for(int j2=0;j2<8;j2++) s[j2] += bf2f(ld.u[j2]);
    }
  }
  union{uint4 q; unsigned short u[8];} st;
  #pragma unroll
  for(int j2=0;j2<8;j2++) st.u[j2] = f2bf(s[j2]);
  *(uint4*)(accb + (size_t)n*E_DIM + base) = st.q;
}

// ---------------- launch ----------------
extern "C" void kernel_launch(void* const* d_in, const int* in_sizes, int n_in,
                              void* d_out, int out_size, void* d_ws, size_t ws_size,
                              hipStream_t stream) {
  const float* x   = (const float*)d_in[0];
  const float* Wq  = (const float*)d_in[1];
  const float* Wk  = (const float*)d_in[2];
  const float* Wv  = (const float*)d_in[3];
  const float* Wo  = (const float*)d_in[4];
  const float* Wr1 = (const float*)d_in[5];
  const float* br1 = (const float*)d_in[6];
  const float* Wr2 = (const float*)d_in[7];
  const float* br2 = (const float*)d_in[8];

  char* ws = (char*)d_ws;
  size_t off = 0;
  auto alloc = [&](size_t bytes)->void*{
    void* p = ws + off;
    off += (bytes + 255) & ~(size_t)255;
    return p;
  };
  unsigned short* xhi   = (unsigned short*)alloc((size_t)N_TOK*E_DIM*2);
  unsigned short* xlo   = (unsigned short*)alloc((size_t)N_TOK*E_DIM*2);
  unsigned short* wr1hi = (unsigned short*)alloc((size_t)E_DIM*1024*2);   // transposed [1024][2048]
  unsigned short* wr1lo = (unsigned short*)alloc((size_t)E_DIM*1024*2);
  unsigned short* wqkvT = (unsigned short*)alloc((size_t)3*E_DIM*E_DIM*2); // [6144][2048]
  unsigned short* woT   = (unsigned short*)alloc((size_t)E_DIM*E_DIM*2);   // contiguous after wqkvT
  void* hv = alloc((size_t)KEXP*NH*CAPN*DH*2);   // max(hbuf 16.8MB, Vg 21MB)
  float* hbuf = (float*)hv;                      // dead after scores_kernel
  unsigned short* Vg = (unsigned short*)hv;      // written by prev_kernel later
  float* scores = (float*)alloc((size_t)N_TOK*4*4);
  float* tokmax = (float*)alloc((size_t)N_TOK*4);
  int*   topkI  = (int*)alloc((size_t)KEXP*CAPN*4);
  float* topv   = (float*)alloc((size_t)KEXP*CAPN*4);
  float* selw   = (float*)alloc((size_t)KEXP*CAPN*4);
  int*   rankof = (int*)alloc((size_t)KEXP*N_TOK*4);
  float* cosT   = (float*)alloc((size_t)CAPN*64*4);
  float* sinT   = (float*)alloc((size_t)CAPN*64*4);
  unsigned short* qkvbuf = (unsigned short*)alloc((size_t)N_TOK*QKV_STRIDE*2);
  unsigned short* oexp = (unsigned short*)alloc((size_t)KEXP*CAPN*E_DIM*2);
  unsigned short* accb = (unsigned short*)alloc((size_t)N_TOK*E_DIM*2);
  if (off > ws_size) return;   // fail loudly (output stays poisoned)

  // Kg (21MB, swizzled) aliases xlo+wr1hi+wr1lo (25.2MB), dead after router GEMM
  unsigned short* Kg = xlo;

  // conversions
  conv_x_kernel<<<(N_TOK*E_DIM/4+255)/256, 256, 0, stream>>>(x, xhi, xlo, N_TOK*E_DIM/4);
  tconv_kernel<<<dim3(1024/32, E_DIM/32), dim3(32,8), 0, stream>>>(Wr1, wr1hi, wr1lo, E_DIM, 1024);
  // fused transpose Wq,Wk,Wv,Wo -> wqkvT(+woT, contiguous)
  tconv4_kernel<<<dim3(E_DIM/32, E_DIM/32, 4), dim3(32,8), 0, stream>>>(Wq, Wk, Wv, Wo, wqkvT);

  // pipelined fused router (3-slot ring, 2 blocks/CU): H = gelu(x@Wr1 + br1)
  gemm_router_p<<<dim3(1024/128, N_TOK/64), 256, 0, stream>>>(xhi, xlo, wr1hi, wr1lo, br1, hbuf);
  scores_kernel<<<N_TOK/4, 256, 0, stream>>>(hbuf, Wr2, br2, scores, tokmax);
  aux_kernel<<<1, 1024, 0, stream>>>(tokmax, ((float*)d_out) + (size_t)N_TOK*E_DIM);
  // exact top-k via parallel rank + per-expert softmax
  rank_kernel<<<dim3(16, KEXP), 256, 0, stream>>>(scores, topkI, topv, rankof);
  selw_kernel<<<KEXP, 1024, 0, stream>>>(topv, selw);
  rope_kernel<<<CAPN*64/256, 256, 0, stream>>>(cosT, sinT);

  // fused QKV projection: [4096][6144] via 128x128 ring GEMM (3 blocks/CU, 2.0 rounds)
  gemm_p<1><<<dim3(QKV_STRIDE/128, N_TOK/128), 512, 0, stream>>>(xhi, wqkvT, qkvbuf, QKV_STRIDE, E_DIM);

  // pre-gather/rope/transpose K,V into dense swizzled tiles
  prerope_k_kernel<<<KEXP*NH*CAPN*16/256, 256, 0, stream>>>(qkvbuf + E_DIM, topkI, cosT, sinT, Kg);
  prev_kernel<<<KEXP*NH*NTILE, 256, 0, stream>>>(qkvbuf + 2*E_DIM, topkI, Vg);

  // gathered causal attention: balanced per-CU work + thinned softmax
  attn_kernel<<<KEXP*NH*NQB, 512, 0, stream>>>(qkvbuf, Kg, Vg, topkI, selw, cosT, sinT, oexp);

  // scatter-accumulate experts -> token rows
  acc_kernel<<<N_TOK, 256, 0, stream>>>(oexp, rankof, accb);

  // final projection -> d_out (128x128 ring GEMM, 512 blocks all co-resident)
  gemm_p<0><<<dim3(E_DIM/128, N_TOK/128), 512, 0, stream>>>(accb, woT, (float*)d_out, E_DIM, E_DIM);
}

// Round 17
// 404.870 us; speedup vs baseline: 1.0572x; 1.0572x over previous
//
#include <hip/hip_runtime.h>
#include <cstdint>
#include <cstddef>

// Problem constants
#define N_TOK 4096
#define E_DIM 2048
#define NH    16
#define DH    128
#define KEXP  4
#define CAPN  1280
#define NTILE 20                 // CAPN/64
#define NQB   10                 // CAPN/128 (attn q-blocks)
#define QKV_STRIDE 6144          // fused QKV output row stride
#define SCALE_QK 0.08838834764831845f
#define LOG2E    1.4426950408889634f
#define NEG_BIG -1e30f

typedef __attribute__((ext_vector_type(4))) float f32x4;
typedef __attribute__((ext_vector_type(8))) short s16x8;

__device__ __forceinline__ float bf2f(unsigned short u){
  union{unsigned int i; float fl;} c; c.i = ((unsigned int)u)<<16; return c.fl;
}
__device__ __forceinline__ unsigned short f2bf(float x){
  union{float fl; unsigned int i;} c; c.fl=x;
  return (unsigned short)((c.i + 0x7FFFu + ((c.i>>16)&1u))>>16);
}
__device__ __forceinline__ f32x4 mfma_bf16(s16x8 a, s16x8 b, f32x4 c){
  asm("v_mfma_f32_16x16x32_bf16 %0, %1, %2, %0" : "+v"(c) : "v"(a), "v"(b));
  return c;
}
// async global->LDS 16B: LDS dest must be lane-linear (base + lane*16)
__device__ __forceinline__ void gl_lds16(const unsigned short* g, unsigned short* l){
  __builtin_amdgcn_global_load_lds(
      (const __attribute__((address_space(1))) unsigned int*)g,
      (__attribute__((address_space(3))) unsigned int*)l, 16, 0, 0);
}

// ---------------- conversions ----------------
__global__ __launch_bounds__(256) void conv_x_kernel(const float* __restrict__ x,
    unsigned short* __restrict__ hi, unsigned short* __restrict__ lo, int n4){
  int idx = blockIdx.x*256 + threadIdx.x;
  if (idx >= n4) return;
  float4 v = ((const float4*)x)[idx];
  float ar[4] = {v.x, v.y, v.z, v.w};
  union{ unsigned short u[4]; uint2 q; } H, L;
  #pragma unroll
  for(int i=0;i<4;i++){
    unsigned short h = f2bf(ar[i]);
    H.u[i] = h;
    L.u[i] = f2bf(ar[i] - bf2f(h));
  }
  ((uint2*)hi)[idx] = H.q;
  ((uint2*)lo)[idx] = L.q;
}

// transpose + f32->bf16 (optionally also lo residual). W[R][C] -> T[C][R]
__global__ __launch_bounds__(256) void tconv_kernel(const float* __restrict__ W,
    unsigned short* __restrict__ Thi, unsigned short* __restrict__ Tlo, int R, int C){
  __shared__ float t[32][33];
  int tx = threadIdx.x, ty = threadIdx.y;   // (32,8)
  int c0 = blockIdx.x*32, r0 = blockIdx.y*32;
  #pragma unroll
  for(int i=0;i<4;i++){
    int r = r0 + ty + i*8;
    t[ty+i*8][tx] = W[(size_t)r*C + c0 + tx];
  }
  __syncthreads();
  #pragma unroll
  for(int i=0;i<4;i++){
    int c = c0 + ty + i*8;
    float v = t[tx][ty+i*8];
    size_t o = (size_t)c*R + r0 + tx;
    unsigned short h = f2bf(v);
    Thi[o] = h;
    if (Tlo) Tlo[o] = f2bf(v - bf2f(h));
  }
}

// fused transpose of 4 ExE weights (Wq,Wk,Wv,Wo) -> contiguous [4][E][E] bf16
__global__ __launch_bounds__(256) void tconv4_kernel(const float* __restrict__ W0,
    const float* __restrict__ W1, const float* __restrict__ W2, const float* __restrict__ W3,
    unsigned short* __restrict__ out){
  __shared__ float t[32][33];
  int z = blockIdx.z;
  const float* W = (z==0)?W0 : (z==1)?W1 : (z==2)?W2 : W3;
  unsigned short* T = out + (size_t)z*E_DIM*E_DIM;
  int tx = threadIdx.x, ty = threadIdx.y;   // (32,8)
  int c0 = blockIdx.x*32, r0 = blockIdx.y*32;
  #pragma unroll
  for(int i=0;i<4;i++){
    int r = r0 + ty + i*8;
    t[ty+i*8][tx] = W[(size_t)r*E_DIM + c0 + tx];
  }
  __syncthreads();
  #pragma unroll
  for(int i=0;i<4;i++){
    int c = c0 + ty + i*8;
    T[(size_t)c*E_DIM + r0 + tx] = f2bf(t[tx][ty+i*8]);
  }
}

// ============ 128x256 BK=32-slab 3-slot-ring pipelined GEMM (T2+T3+T4+T5) ============
// r15 proven configuration: 72KB LDS -> 2 blocks/CU; steady vmcnt(3); 16 MFMA/phase/wave.
template<int OUTBF>
__global__ __launch_bounds__(512, 2) void gemm_p(
    const unsigned short* __restrict__ A, const unsigned short* __restrict__ Bt,
    void* __restrict__ Cp, int N, int Kd){
  __shared__ __align__(16) unsigned short lds[3*12288];   // 72 KB
  const int tid = threadIdx.x;
  const int w = tid>>6, lane = tid&63, g = lane>>4, r16 = lane&15;
  const int wm = w>>2, wn = w&3;                   // 2M x 4N waves
  const int mb = blockIdx.y, nb = blockIdx.x;
  const unsigned short* Ab = A  + (size_t)mb*128*Kd;
  const unsigned short* Bb = Bt + (size_t)nb*256*Kd;
  const int PMAX = Kd >> 5;                        // K/32 phases

  f32x4 acc[4][4];
  #pragma unroll
  for(int i=0;i<4;i++)
    #pragma unroll
    for(int j=0;j<4;j++) acc[i][j] = f32x4{0.f,0.f,0.f,0.f};

  auto stageP = [&](int Pst, int slot){
    unsigned short* base = &lds[slot*12288];
    const int col = Pst*32;
    {
      int row = tid>>2, ch = tid&3;
      int sc = ch ^ ((row>>1)&3);
      gl_lds16(Ab + (size_t)row*Kd + col + sc*8, base + tid*8);
    }
    #pragma unroll
    for(int i=0;i<2;i++){
      int n = i*512 + tid;
      int rw = n>>2, c2 = n&3;
      int s2 = c2 ^ ((rw>>1)&3);
      gl_lds16(Bb + (size_t)rw*Kd + col + s2*8, base + 4096 + n*8);
    }
  };
  const int xoff = (g ^ ((r16>>1)&3)) << 3;

  // prologue: phases 0,1 into slots 0,1; wait phase-0's unit (leave stage(1) in flight)
  stageP(0,0); stageP(1,1);
  asm volatile("s_waitcnt vmcnt(3)" ::: "memory");
  __builtin_amdgcn_s_barrier();

  int sR = 0, sW = 2;
  for(int P=0; P<PMAX; ++P){
    const unsigned short* base = &lds[sR*12288];
    s16x8 af[4], bfv[4];
    #pragma unroll
    for(int mf=0;mf<4;mf++)
      af[mf] = *(const s16x8*)&base[(wm*64 + mf*16 + r16)*32 + xoff];
    #pragma unroll
    for(int nf=0;nf<4;nf++)
      bfv[nf] = *(const s16x8*)&base[4096 + (wn*64 + nf*16 + r16)*32 + xoff];
    if (P+2 < PMAX) stageP(P+2, sW);
    __builtin_amdgcn_s_setprio(1);
    #pragma unroll
    for(int mf=0;mf<4;mf++)
      #pragma unroll
      for(int nf=0;nf<4;nf++)
        acc[mf][nf] = mfma_bf16(af[mf], bfv[nf], acc[mf][nf]);
    __builtin_amdgcn_s_setprio(0);
    if      (P+2 < PMAX) asm volatile("s_waitcnt vmcnt(3)" ::: "memory");
    else                 asm volatile("s_waitcnt vmcnt(0)" ::: "memory");
    __builtin_amdgcn_s_barrier();
    sR = (sR==2) ? 0 : sR+1;
    sW = (sW==2) ? 0 : sW+1;
  }

  const int rowb = mb*128 + wm*64, colb = nb*256 + wn*64;
  #pragma unroll
  for(int mf=0;mf<4;mf++)
    #pragma unroll
    for(int nf=0;nf<4;nf++)
      #pragma unroll
      for(int r=0;r<4;r++){
        int rr = rowb + mf*16 + 4*g + r;
        int cc = colb + nf*16 + r16;
        size_t o = (size_t)rr*N + cc;
        if (OUTBF) ((unsigned short*)Cp)[o] = f2bf(acc[mf][nf][r]);
        else       ((float*)Cp)[o] = acc[mf][nf][r];
      }
}

// ============ router GEMM on the 3-slot-ring skeleton: H = gelu(x@Wr1+br1) ============
__global__ __launch_bounds__(256, 2) void gemm_router_p(
    const unsigned short* __restrict__ Ahi, const unsigned short* __restrict__ Alo,
    const unsigned short* __restrict__ Bhi, const unsigned short* __restrict__ Blo,
    const float* __restrict__ br1, float* __restrict__ H){
  __shared__ __align__(16) unsigned short lds[3*12288];   // 72 KB
  const int tid = threadIdx.x;
  const int w = tid>>6, lane = tid&63, g = lane>>4, r16 = lane&15;
  const int mb = blockIdx.y, nb = blockIdx.x;
  const unsigned short* AbH = Ahi + (size_t)mb*64*E_DIM;
  const unsigned short* AbL = Alo + (size_t)mb*64*E_DIM;
  const unsigned short* BbH = Bhi + (size_t)nb*128*E_DIM;
  const unsigned short* BbL = Blo + (size_t)nb*128*E_DIM;
  const int PMAX = E_DIM >> 5;   // 64

  f32x4 acc[4][2];
  #pragma unroll
  for(int i=0;i<4;i++){ acc[i][0]=f32x4{0.f,0.f,0.f,0.f}; acc[i][1]=f32x4{0.f,0.f,0.f,0.f}; }

  auto stageP = [&](int Pst, int slot){
    unsigned short* base = &lds[slot*12288];
    const int col = Pst*32;
    {
      int row = tid>>2, ch = tid&3;              // 64 rows x 4 chunks
      int sc = ch ^ ((row>>1)&3);
      size_t go = (size_t)row*E_DIM + col + sc*8;
      gl_lds16(AbH + go, base +        tid*8);
      gl_lds16(AbL + go, base + 2048 + tid*8);
    }
    #pragma unroll
    for(int i=0;i<2;i++){
      int n = i*256 + tid;                       // 128 rows x 4 chunks
      int row = n>>2, ch = n&3;
      int sc = ch ^ ((row>>1)&3);
      size_t go = (size_t)row*E_DIM + col + sc*8;
      gl_lds16(BbH + go, base + 4096 + n*8);
      gl_lds16(BbL + go, base + 8192 + n*8);
    }
  };
  const int xoff = (g ^ ((r16>>1)&3)) << 3;

  stageP(0,0); stageP(1,1);
  asm volatile("s_waitcnt vmcnt(6)" ::: "memory");
  __builtin_amdgcn_s_barrier();

  int sR = 0, sW = 2;
  for(int P=0; P<PMAX; ++P){
    const unsigned short* base = &lds[sR*12288];
    s16x8 ah[4], al[4], bh[2], bl[2];
    #pragma unroll
    for(int mf=0;mf<4;mf++){
      int ro = (mf*16 + r16)*32 + xoff;
      ah[mf] = *(const s16x8*)&base[ro];
      al[mf] = *(const s16x8*)&base[2048 + ro];
    }
    #pragma unroll
    for(int nf=0;nf<2;nf++){
      int rb = (w*32 + nf*16 + r16)*32 + xoff;
      bh[nf] = *(const s16x8*)&base[4096 + rb];
      bl[nf] = *(const s16x8*)&base[8192 + rb];
    }
    if (P+2 < PMAX) stageP(P+2, sW);
    __builtin_amdgcn_s_setprio(1);
    #pragma unroll
    for(int mf=0;mf<4;mf++)
      #pragma unroll
      for(int nf=0;nf<2;nf++){
        acc[mf][nf] = mfma_bf16(ah[mf], bh[nf], acc[mf][nf]);
        acc[mf][nf] = mfma_bf16(ah[mf], bl[nf], acc[mf][nf]);
        acc[mf][nf] = mfma_bf16(al[mf], bh[nf], acc[mf][nf]);
      }
    __builtin_amdgcn_s_setprio(0);
    if      (P+2 < PMAX) asm volatile("s_waitcnt vmcnt(6)" ::: "memory");
    else                 asm volatile("s_waitcnt vmcnt(0)" ::: "memory");
    __builtin_amdgcn_s_barrier();
    sR = (sR==2) ? 0 : sR+1;
    sW = (sW==2) ? 0 : sW+1;
  }

  const int rowb = mb*64, colb = nb*128 + w*32;
  #pragma unroll
  for(int mf=0;mf<4;mf++)
    #pragma unroll
    for(int nf=0;nf<2;nf++)
      #pragma unroll
      for(int r=0;r<4;r++){
        int rr = rowb + mf*16 + 4*g + r;
        int cc = colb + nf*16 + r16;
        float v = acc[mf][nf][r] + br1[cc];
        H[(size_t)rr*1024 + cc] = 0.5f*v*(1.0f + erff(v*0.70710678118654752f));
      }
}

// ---------------- router scores ----------------
__global__ __launch_bounds__(256) void scores_kernel(const float* __restrict__ h,
    const float* __restrict__ Wr2, const float* __restrict__ br2,
    float* __restrict__ scores, float* __restrict__ tokmax){
  int tid = threadIdx.x;
  int n = blockIdx.x*4 + (tid>>6);
  int lane = tid & 63;
  const float* hr = h + (size_t)n*1024;
  float s0=0,s1=0,s2=0,s3=0;
  #pragma unroll
  for(int i=0;i<16;i++){
    int j = lane + i*64;
    float hv = hr[j];
    float4 wv = *(const float4*)(Wr2 + (size_t)j*4);
    s0 += hv*wv.x; s1 += hv*wv.y; s2 += hv*wv.z; s3 += hv*wv.w;
  }
  #pragma unroll
  for(int m=32;m>=1;m>>=1){
    s0 += __shfl_xor(s0,m); s1 += __shfl_xor(s1,m);
    s2 += __shfl_xor(s2,m); s3 += __shfl_xor(s3,m);
  }
  if (lane==0){
    s0+=br2[0]; s1+=br2[1]; s2+=br2[2]; s3+=br2[3];
    scores[n*4+0]=s0; scores[n*4+1]=s1; scores[n*4+2]=s2; scores[n*4+3]=s3;
    tokmax[n]=fmaxf(fmaxf(s0,s1),fmaxf(s2,s3));
  }
}

__global__ __launch_bounds__(1024) void aux_kernel(const float* __restrict__ tokmax, float* __restrict__ out_aux){
  __shared__ float red[1024];
  int t = threadIdx.x;
  red[t] = tokmax[t] + tokmax[t+1024] + tokmax[t+2048] + tokmax[t+3072];
  __syncthreads();
  for(int k=512;k>=1;k>>=1){ if(t<k) red[t]+=red[t+k]; __syncthreads(); }
  if (t==0) out_aux[0] = -red[0]/4096.0f;
}

// ---------------- exact top-k via parallel rank ----------------
__global__ __launch_bounds__(256) void rank_kernel(const float* __restrict__ scores,
    int* __restrict__ topk_idx, float* __restrict__ topv, int* __restrict__ rank_of){
  __shared__ unsigned long long keys[4096];   // 32KB
  const int e = blockIdx.y, blk = blockIdx.x, tid = threadIdx.x;
  for(int i=tid;i<4096;i+=256){
    unsigned u = __float_as_uint(scores[i*4+e]);
    unsigned m = (u & 0x80000000u) ? ~u : (u | 0x80000000u);
    keys[i] = (((unsigned long long)m)<<32) | (unsigned)(4095-i);
  }
  __syncthreads();
  const int i = blk*256 + tid;
  const unsigned long long mykey = keys[i];
  int cnt = 0;
  #pragma unroll 8
  for(int j=0;j<4096;j++) cnt += (keys[j] > mykey) ? 1 : 0;
  if (cnt < CAPN){
    topk_idx[e*CAPN + cnt] = i;
    topv[e*CAPN + cnt]     = scores[i*4+e];
    rank_of[e*4096 + i]    = cnt;
  } else {
    rank_of[e*4096 + i]    = -1;
  }
}

// per-expert softmax over the CAPN sorted top values -> sel_w
__global__ __launch_bounds__(1024) void selw_kernel(const float* __restrict__ topv,
    float* __restrict__ sel_w){
  __shared__ float red[1024];
  const int e = blockIdx.x, t = threadIdx.x;
  const float mx = topv[e*CAPN];        // rank 0 == max
  float p0 = expf(topv[e*CAPN + t] - mx);
  float p1 = (t + 1024 < CAPN) ? expf(topv[e*CAPN + t + 1024] - mx) : 0.f;
  red[t] = p0 + p1;
  __syncthreads();
  for(int k=512;k>=1;k>>=1){ if(t<k) red[t]+=red[t+k]; __syncthreads(); }
  const float denom = red[0];
  sel_w[e*CAPN + t] = p0/denom;
  if (t + 1024 < CAPN) sel_w[e*CAPN + t + 1024] = p1/denom;
}

// ---------------- RoPE tables [CAPN][64] ----------------
__global__ __launch_bounds__(256) void rope_kernel(float* __restrict__ cosT, float* __restrict__ sinT){
  int idx = blockIdx.x*256 + threadIdx.x;
  int p = idx>>6, dm = idx&63;
  float inv = powf(10000.0f, -(float)dm/64.0f);
  float ang = (float)p*inv;
  cosT[idx]=cosf(ang);
  sinT[idx]=sinf(ang);
}

// ---------------- pre-gather + pre-rope K into swizzled tiles ----------------
__global__ __launch_bounds__(256) void prerope_k_kernel(const unsigned short* __restrict__ kb,
    const int* __restrict__ topk_idx, const float* __restrict__ cosT, const float* __restrict__ sinT,
    unsigned short* __restrict__ Kg){
  int idx = blockIdx.x*256 + threadIdx.x;   // exact 4*16*1280*16
  int ch = idx & 15;
  int rest = idx >> 4;
  int rank = rest % CAPN;
  int he = rest / CAPN;           // e*16+h
  int e = he >> 4, h = he & 15;
  int tok = topk_idx[e*CAPN + rank];
  int d0 = ch*8;
  const unsigned short* krow = kb + (size_t)tok*QKV_STRIDE + h*DH;
  unsigned short held[8], part[8];
  *(uint4*)held = *(const uint4*)(krow + d0);
  *(uint4*)part = *(const uint4*)(krow + (d0^64));
  const float* cr = cosT + rank*64;
  const float* sr = sinT + rank*64;
  float sgn = (d0<64) ? -1.f : 1.f;
  unsigned short outv[8];
  #pragma unroll
  for(int jj=0;jj<8;jj++){
    int dm = (d0+jj)&63;
    outv[jj] = f2bf(bf2f(held[jj])*cr[dm] + sgn*bf2f(part[jj])*sr[dm]);
  }
  int t = rank >> 6, row = rank & 63;
  size_t tbase = ((size_t)(he)*NTILE + t) * 8192;
  *(uint4*)(Kg + tbase + row*128 + ((ch ^ (row&7))<<3)) = *(uint4*)outv;
}

// ---------------- pre-gather + transpose V into swizzled tiles ----------------
__global__ __launch_bounds__(256) void prev_kernel(const unsigned short* __restrict__ vb,
    const int* __restrict__ topk_idx, unsigned short* __restrict__ Vg){
  __shared__ __align__(16) unsigned short T2[128][72];
  int bid = blockIdx.x;           // e*320 + h*20 + t
  int t = bid % NTILE, h = (bid/NTILE) & 15, e = bid/(NTILE*NH);
  int tid = threadIdx.x, lane = tid & 63, dchb = tid >> 6;
  int tok = topk_idx[e*CAPN + t*64 + lane];
  const unsigned short* vrow = vb + (size_t)tok*QKV_STRIDE + h*DH;
  #pragma unroll
  for(int i=0;i<4;i++){
    int d0 = (dchb + i*4)*8;
    unsigned short vv[8];
    *(uint4*)vv = *(const uint4*)(vrow + d0);
    #pragma unroll
    for(int j=0;j<8;j++) T2[d0+j][lane] = vv[j];   // lane-consecutive: conflict-free
  }
  __syncthreads();
  unsigned short* out = Vg + ((size_t)(e*NH+h)*NTILE + t)*8192;
  #pragma unroll
  for(int i=0;i<4;i++){
    int c = i*256 + tid;
    int d = c>>3, ch = c&7;
    *(uint4*)(out + d*64 + ((ch ^ (d&7))<<3)) = *(const uint4*)&T2[d][ch*8];
  }
}

// ---------------- gathered causal flash attention (128 Q rows / block, 8 waves) ----------------
// Balanced id->qb2 decode; per-lane l partials; T13 defer-max; fully-masked-wave skip
// on the last diagonal tile (exact-math no-op: P==0 for those waves).
__global__ __launch_bounds__(512) void attn_kernel(
    const unsigned short* __restrict__ qb,
    const unsigned short* __restrict__ Kg, const unsigned short* __restrict__ Vg,
    const int* __restrict__ topk_idx, const float* __restrict__ sel_w,
    const float* __restrict__ cosT, const float* __restrict__ sinT,
    unsigned short* __restrict__ oexp){
  __shared__ __align__(16) unsigned short Ks[8192];
  __shared__ __align__(16) unsigned short Vs[8192];
  __shared__ __align__(16) unsigned short Ps[8][16][72];
  // balanced decode: layer0 qb2 {9,8,7,6}; layer1 {2,3,4,5} (pairwise sum 26); layer2 {0,1}
  const int id = blockIdx.x;
  int qb2, ehi;
  if (id < 512){
    const int layer = id >> 8;         // 0 or 1
    const int j = id & 255;
    const int cat = j >> 6;            // 0..3
    ehi = j & 63;
    qb2 = layer ? (2 + cat) : (9 - cat);
  } else {
    const int j = id - 512;
    qb2 = j >> 6;                      // 0 or 1
    ehi = j & 63;
  }
  const int e = ehi >> 4, hh = ehi & 15;
  const int tid = threadIdx.x, w = tid>>6, lane = tid&63, g = lane>>4, r16 = lane&15;
  const int* idxE = topk_idx + e*CAPN;
  const unsigned short* Kgb = Kg + (size_t)(e*NH+hh)*CAPN*DH;
  const unsigned short* Vgb = Vg + (size_t)(e*NH+hh)*CAPN*DH;
  const int ktmax = 2*qb2 + 1;
  const float THR = 8.0f*LOG2E;        // defer-max threshold (log2 domain)

  s16x8 aq[4];
  {
    int qr = qb2*128 + w*16 + r16;
    int tok = idxE[qr];
    const unsigned short* qrow = qb + (size_t)tok*QKV_STRIDE + hh*DH;
    const float* cr = cosT + qr*64;
    const float* sr = sinT + qr*64;
    #pragma unroll
    for(int s=0;s<4;s++){
      int d0 = s*32 + 8*g;
      unsigned short held[8], part[8];
      *(uint4*)held = *(const uint4*)(qrow + d0);
      *(uint4*)part = *(const uint4*)(qrow + (d0^64));
      float sgn = (d0<64) ? -1.f : 1.f;
      union{ s16x8 v; unsigned short u[8]; } fr;
      #pragma unroll
      for(int jj=0;jj<8;jj++){
        int dm = (d0+jj)&63;
        float val = bf2f(held[jj])*cr[dm] + sgn*bf2f(part[jj])*sr[dm];
        fr.u[jj] = f2bf(val * (SCALE_QK*LOG2E));
      }
      aq[s] = fr.v;
    }
  }
  float m_r[4], l_r[4];   // l_r: PER-LANE partial sums (reduced across 16 lanes at epilogue)
  f32x4 o[8];
  #pragma unroll
  for(int r=0;r<4;r++){ m_r[r]=-INFINITY; l_r[r]=0.f; }
  #pragma unroll
  for(int f2=0;f2<8;f2++) o[f2]=f32x4{0.f,0.f,0.f,0.f};

  for(int kt=0; kt<=ktmax; kt++){
    // stage K(kt), V(kt) into single buffers (prev readers done: barrier at tile end)
    {
      const unsigned short* Ksrc = Kgb + (size_t)kt*8192;
      const unsigned short* Vsrc = Vgb + (size_t)kt*8192;
      #pragma unroll
      for(int i=0;i<2;i++){ int c=i*512+tid; gl_lds16(Ksrc + c*8, &Ks[c*8]); }
      #pragma unroll
      for(int i=0;i<2;i++){ int c=i*512+tid; gl_lds16(Vsrc + c*8, &Vs[c*8]); }
    }
    asm volatile("s_waitcnt vmcnt(0)" ::: "memory");
    __builtin_amdgcn_s_barrier();
    // last diagonal tile: waves 0-3 are fully masked (P==0) -> skip their compute
    const bool active = !(kt == ktmax && w < 4);
    if (active){
      // QK^T
      f32x4 sfr[4];
      __builtin_amdgcn_s_setprio(1);
      #pragma unroll
      for(int fc=0;fc<4;fc++){
        f32x4 a4 = f32x4{0.f,0.f,0.f,0.f};
        const int row = fc*16 + r16;
        #pragma unroll
        for(int s=0;s<4;s++){
          s16x8 bk = *(const s16x8*)&Ks[row*128 + (((s*4+g) ^ (r16&7))<<3)];
          a4 = mfma_bf16(aq[s], bk, a4);
        }
        sfr[fc] = a4;
      }
      __builtin_amdgcn_s_setprio(0);
      if (kt >= 2*qb2){   // diagonal tiles only
        #pragma unroll
        for(int fc=0;fc<4;fc++)
          #pragma unroll
          for(int r=0;r<4;r++){
            int qrank  = qb2*128 + w*16 + 4*g + r;
            int kvrank = kt*64 + fc*16 + r16;
            if (kvrank > qrank) sfr[fc][r] = NEG_BIG;
          }
      }
      // online softmax (exp2 domain), defer-max; l is per-lane partial
      float corr[4];
      bool need = false;
      #pragma unroll
      for(int r=0;r<4;r++){
        float mx = fmaxf(fmaxf(sfr[0][r],sfr[1][r]), fmaxf(sfr[2][r],sfr[3][r]));
        #pragma unroll
        for(int mk=1;mk<16;mk<<=1) mx = fmaxf(mx, __shfl_xor(mx,mk));
        bool trig = mx > m_r[r] + THR;
        float nm = trig ? mx : m_r[r];
        need = need || trig;
        corr[r] = exp2f(m_r[r]-nm);   // == 1.0 when !trig
        m_r[r] = nm;
      }
      if (__any(need)){
        #pragma unroll
        for(int f2=0;f2<8;f2++)
          #pragma unroll
          for(int r=0;r<4;r++) o[f2][r] *= corr[r];
        #pragma unroll
        for(int r=0;r<4;r++) l_r[r] *= corr[r];
      }
      #pragma unroll
      for(int fc=0;fc<4;fc++)
        #pragma unroll
        for(int r=0;r<4;r++){
          float p = exp2f(sfr[fc][r] - m_r[r]);
          l_r[r] += p;
          Ps[w][4*g+r][fc*16+r16] = f2bf(p);
        }
      // PV (Ps wave-private: lgkm-ordered within wave)
      __builtin_amdgcn_s_setprio(1);
      #pragma unroll
      for(int ks=0;ks<2;ks++){
        s16x8 pa = *(const s16x8*)&Ps[w][r16][ks*32 + 8*g];
        #pragma unroll
        for(int fd=0;fd<8;fd++){
          const int row = fd*16 + r16;
          s16x8 vf = *(const s16x8*)&Vs[row*64 + (((ks*4+g) ^ (r16&7))<<3)];
          o[fd] = mfma_bf16(pa, vf, o[fd]);
        }
      }
      __builtin_amdgcn_s_setprio(0);
    }
    if (kt < ktmax) __builtin_amdgcn_s_barrier();   // readers done -> next stage may overwrite
  }
  // epilogue: reduce per-lane l partials across the 16-lane row group, then scale+store
  #pragma unroll
  for(int r=0;r<4;r++){
    float ts = l_r[r];
    #pragma unroll
    for(int mk=1;mk<16;mk<<=1) ts += __shfl_xor(ts,mk);
    int qrank = qb2*128 + w*16 + 4*g + r;
    float fac = sel_w[e*CAPN + qrank] / ts;
    #pragma unroll
    for(int fd=0;fd<8;fd++){
      oexp[((size_t)(e*CAPN + qrank))*E_DIM + hh*DH + fd*16 + r16] = f2bf(o[fd][r]*fac);
    }
  }
}

// ---------------- scatter-accumulate over experts ----------------
__global__ __launch_bounds__(256) void acc_kernel(const unsigned short* __restrict__ oexp,
    const int* __restrict__ rank_of, unsigned short* __restrict__ accb){
  int n = blockIdx.x, t = threadIdx.x;
  int base = t*8;
  float s[8] = {0,0,0,0,0,0,0,0};
  #pragma unroll
  for(int e=0;e<4;e++){
    int r = rank_of[e*4096+n];
    if (r>=0){
      union{uint4 q; unsigned short u[8];} ld;
      ld.q = *(const uint4*)(oexp + ((size_t)(e*CAPN+r))*E_DIM + base);
      #pragma unroll
      for(int j2=0;j2<8;j2++) s[j2] += bf2f(ld.u[j2]);
    }
  }
  union{uint4 q; unsigned short u[8];} st;
  #pragma unroll
  for(int j2=0;j2<8;j2++) st.u[j2] = f2bf(s[j2]);
  *(uint4*)(accb + (size_t)n*E_DIM + base) = st.q;
}

// ---------------- launch ----------------
extern "C" void kernel_launch(void* const* d_in, const int* in_sizes, int n_in,
                              void* d_out, int out_size, void* d_ws, size_t ws_size,
                              hipStream_t stream) {
  const float* x   = (const float*)d_in[0];
  const float* Wq  = (const float*)d_in[1];
  const float* Wk  = (const float*)d_in[2];
  const float* Wv  = (const float*)d_in[3];
  const float* Wo  = (const float*)d_in[4];
  const float* Wr1 = (const float*)d_in[5];
  const float* br1 = (const float*)d_in[6];
  const float* Wr2 = (const float*)d_in[7];
  const float* br2 = (const float*)d_in[8];

  char* ws = (char*)d_ws;
  size_t off = 0;
  auto alloc = [&](size_t bytes)->void*{
    void* p = ws + off;
    off += (bytes + 255) & ~(size_t)255;
    return p;
  };
  unsigned short* xhi   = (unsigned short*)alloc((size_t)N_TOK*E_DIM*2);
  unsigned short* xlo   = (unsigned short*)alloc((size_t)N_TOK*E_DIM*2);
  unsigned short* wr1hi = (unsigned short*)alloc((size_t)E_DIM*1024*2);   // transposed [1024][2048]
  unsigned short* wr1lo = (unsigned short*)alloc((size_t)E_DIM*1024*2);
  unsigned short* wqkvT = (unsigned short*)alloc((size_t)3*E_DIM*E_DIM*2); // [6144][2048]
  unsigned short* woT   = (unsigned short*)alloc((size_t)E_DIM*E_DIM*2);   // contiguous after wqkvT
  void* hv = alloc((size_t)KEXP*NH*CAPN*DH*2);   // max(hbuf 16.8MB, Vg 21MB)
  float* hbuf = (float*)hv;                      // dead after scores_kernel
  unsigned short* Vg = (unsigned short*)hv;      // written by prev_kernel later
  float* scores = (float*)alloc((size_t)N_TOK*4*4);
  float* tokmax = (float*)alloc((size_t)N_TOK*4);
  int*   topkI  = (int*)alloc((size_t)KEXP*CAPN*4);
  float* topv   = (float*)alloc((size_t)KEXP*CAPN*4);
  float* selw   = (float*)alloc((size_t)KEXP*CAPN*4);
  int*   rankof = (int*)alloc((size_t)KEXP*N_TOK*4);
  float* cosT   = (float*)alloc((size_t)CAPN*64*4);
  float* sinT   = (float*)alloc((size_t)CAPN*64*4);
  unsigned short* qkvbuf = (unsigned short*)alloc((size_t)N_TOK*QKV_STRIDE*2);
  unsigned short* oexp = (unsigned short*)alloc((size_t)KEXP*CAPN*E_DIM*2);
  unsigned short* accb = (unsigned short*)alloc((size_t)N_TOK*E_DIM*2);
  if (off > ws_size) return;   // fail loudly (output stays poisoned)

  // Kg (21MB, swizzled) aliases xlo+wr1hi+wr1lo (25.2MB), dead after router GEMM
  unsigned short* Kg = xlo;

  // conversions
  conv_x_kernel<<<(N_TOK*E_DIM/4+255)/256, 256, 0, stream>>>(x, xhi, xlo, N_TOK*E_DIM/4);
  tconv_kernel<<<dim3(1024/32, E_DIM/32), dim3(32,8), 0, stream>>>(Wr1, wr1hi, wr1lo, E_DIM, 1024);
  // fused transpose Wq,Wk,Wv,Wo -> wqkvT(+woT, contiguous)
  tconv4_kernel<<<dim3(E_DIM/32, E_DIM/32, 4), dim3(32,8), 0, stream>>>(Wq, Wk, Wv, Wo, wqkvT);

  // pipelined fused router (3-slot ring, 2 blocks/CU): H = gelu(x@Wr1 + br1)
  gemm_router_p<<<dim3(1024/128, N_TOK/64), 256, 0, stream>>>(xhi, xlo, wr1hi, wr1lo, br1, hbuf);
  scores_kernel<<<N_TOK/4, 256, 0, stream>>>(hbuf, Wr2, br2, scores, tokmax);
  aux_kernel<<<1, 1024, 0, stream>>>(tokmax, ((float*)d_out) + (size_t)N_TOK*E_DIM);
  // exact top-k via parallel rank + per-expert softmax
  rank_kernel<<<dim3(16, KEXP), 256, 0, stream>>>(scores, topkI, topv, rankof);
  selw_kernel<<<KEXP, 1024, 0, stream>>>(topv, selw);
  rope_kernel<<<CAPN*64/256, 256, 0, stream>>>(cosT, sinT);

  // fused QKV projection: [4096][6144] via 128x256 3-slot-ring GEMM (r15 proven config)
  gemm_p<1><<<dim3(QKV_STRIDE/256, N_TOK/128), 512, 0, stream>>>(xhi, wqkvT, qkvbuf, QKV_STRIDE, E_DIM);

  // pre-gather/rope/transpose K,V into dense swizzled tiles
  prerope_k_kernel<<<KEXP*NH*CAPN*16/256, 256, 0, stream>>>(qkvbuf + E_DIM, topkI, cosT, sinT, Kg);
  prev_kernel<<<KEXP*NH*NTILE, 256, 0, stream>>>(qkvbuf + 2*E_DIM, topkI, Vg);

  // gathered causal attention: balanced per-CU work + thinned softmax + masked-wave skip
  attn_kernel<<<KEXP*NH*NQB, 512, 0, stream>>>(qkvbuf, Kg, Vg, topkI, selw, cosT, sinT, oexp);

  // scatter-accumulate experts -> token rows
  acc_kernel<<<N_TOK, 256, 0, stream>>>(oexp, rankof, accb);

  // final projection -> d_out (128x256 3-slot-ring GEMM)
  gemm_p<0><<<dim3(E_DIM/256, N_TOK/128), 512, 0, stream>>>(accb, woT, (float*)d_out, E_DIM, E_DIM);
}